// Round 1
// baseline (5447.907 us; speedup 1.0000x reference)
//
#include <hip/hip_runtime.h>
#include <hip/hip_bf16.h>

// Problem constants
#define BB 32
#define LL 128
#define DD 400
#define KK 40

// ---------------------------------------------------------------------------
// Kernel 0: SD[b,k,h] = W_d[k] . h[b,h]    SE[b,k,c] = W_e[k] . c[b,c]
// grid: B*K blocks, 256 threads
// ---------------------------------------------------------------------------
__global__ __launch_bounds__(256) void k_sdse(
    const float* __restrict__ H, const float* __restrict__ C,
    const float* __restrict__ Wd, const float* __restrict__ We,
    float* __restrict__ SD, float* __restrict__ SE)
{
    const int k = blockIdx.x % KK;
    const int b = blockIdx.x / KK;
    const int t = threadIdx.x;
    __shared__ float wd[DD], we[DD];
    for (int f = t; f < DD; f += 256) { wd[f] = Wd[k*DD + f]; we[f] = We[k*DD + f]; }
    __syncthreads();
    const int row = t & 127;
    const float* src = (t < 128) ? (H + (size_t)(b*LL + row)*DD)
                                 : (C + (size_t)(b*LL + row)*DD);
    const float* w = (t < 128) ? wd : we;
    float s = 0.f;
    for (int d = 0; d < DD; d += 4) {
        float4 v = *(const float4*)(src + d);
        s = fmaf(v.x, w[d+0], s);
        s = fmaf(v.y, w[d+1], s);
        s = fmaf(v.z, w[d+2], s);
        s = fmaf(v.w, w[d+3], s);
    }
    if (t < 128) SD[(b*KK + k)*LL + row] = s;
    else         SE[(b*KK + k)*LL + row] = s;
}

// ---------------------------------------------------------------------------
// Kernel 1: bilinear energies + exp-accumulate A, and gold-arc tgt accumulate.
// grid: (4 h-tiles, K, B), 256 threads. Per block: h rows [h0,h0+32), all c.
//   Phase A: T[hh][e] = sum_d h[b,h0+hh,d] * U[k,d,e]   (reg accumulate)
//   Phase B: S[hh][c] = sum_e T[hh][e] * c[b,c,e]       (LDS c chunks)
//   Epilogue: eng = S + sd + se + b[k]; A += exp(eng) (masked, off-diag);
//             if (tags[b,c]==k && heads[b,c]==h) tgt[b] += eng*mh*mc
// ---------------------------------------------------------------------------
__global__ __launch_bounds__(256) void k_bil(
    const float* __restrict__ H, const float* __restrict__ C,
    const float* __restrict__ U, const float* __restrict__ bvec,
    const float* __restrict__ mask, const int* __restrict__ heads,
    const int* __restrict__ tags,
    const float* __restrict__ SD, const float* __restrict__ SE,
    float* __restrict__ A, float* __restrict__ tgt)
{
    const int tile = blockIdx.x;   // 0..3
    const int k    = blockIdx.y;   // 0..39
    const int b    = blockIdx.z;   // 0..31
    const int h0   = tile * 32;
    const int t    = threadIdx.x;

    // sbufA: phase A = hT[d*36+hh] (400*36=14400 floats, 16B-aligned rows)
    //        phase B = c chunk ccbuf[cL*81+e] (128*81=10368 floats)
    __shared__ float sbufA[DD*36];
    __shared__ float T2[32*401];

    // stage h tile transposed: hT[d][hh]
    for (int f = t; f < 32*DD; f += 256) {
        int hh = f / DD, d = f - hh*DD;
        sbufA[d*36 + hh] = H[(size_t)(b*LL + h0 + hh)*DD + d];
    }
    __syncthreads();

    // Phase A: thread owns columns e0=t, e1=t+256 for all 32 hh.
    float acc0[32], acc1[32];
#pragma unroll
    for (int i = 0; i < 32; ++i) { acc0[i] = 0.f; acc1[i] = 0.f; }
    const int e0 = t, e1 = t + 256;
    const bool has1 = (e1 < DD);
    const float* Ubase = U + (size_t)k * DD * DD;
    for (int d = 0; d < DD; ++d) {
        const float* Urow = Ubase + (size_t)d * DD;
        float u0 = Urow[e0];
        float u1 = has1 ? Urow[e1] : 0.f;
        const float4* hp = (const float4*)(&sbufA[d*36]);
#pragma unroll
        for (int q = 0; q < 8; ++q) {
            float4 hv = hp[q];
            acc0[4*q+0] = fmaf(hv.x, u0, acc0[4*q+0]);
            acc0[4*q+1] = fmaf(hv.y, u0, acc0[4*q+1]);
            acc0[4*q+2] = fmaf(hv.z, u0, acc0[4*q+2]);
            acc0[4*q+3] = fmaf(hv.w, u0, acc0[4*q+3]);
            acc1[4*q+0] = fmaf(hv.x, u1, acc1[4*q+0]);
            acc1[4*q+1] = fmaf(hv.y, u1, acc1[4*q+1]);
            acc1[4*q+2] = fmaf(hv.z, u1, acc1[4*q+2]);
            acc1[4*q+3] = fmaf(hv.w, u1, acc1[4*q+3]);
        }
    }
#pragma unroll
    for (int hh = 0; hh < 32; ++hh) {
        T2[hh*401 + e0] = acc0[hh];
        if (has1) T2[hh*401 + e1] = acc1[hh];
    }
    __syncthreads();

    // Phase B: thread owns hh = t>>3, c = (t&7) + 8*j for j=0..15
    const int hh = t >> 3;
    const int cb = t & 7;
    float s[16];
#pragma unroll
    for (int j = 0; j < 16; ++j) s[j] = 0.f;

    for (int ec0 = 0; ec0 < DD; ec0 += 80) {
        __syncthreads();   // previous consumers of sbufA done
        for (int f = t; f < 128*80; f += 256) {
            int cL = f / 80, e = f - cL*80;
            sbufA[cL*81 + e] = C[(size_t)(b*LL + cL)*DD + ec0 + e];
        }
        __syncthreads();
        for (int e = 0; e < 80; ++e) {
            float tv = T2[hh*401 + ec0 + e];
#pragma unroll
            for (int j = 0; j < 16; ++j) {
                s[j] = fmaf(tv, sbufA[(cb + 8*j)*81 + e], s[j]);
            }
        }
    }

    // Epilogue
    const int gh = h0 + hh;
    const float mh = mask[b*LL + gh];
    const float sdv = SD[(b*KK + k)*LL + gh];
    const float bk = bvec[k];
    float* Arow = A + (size_t)(b*LL + gh)*LL;
#pragma unroll
    for (int j = 0; j < 16; ++j) {
        int cc = cb + 8*j;
        if (cc == gh) continue;                 // diagonal: -inf -> A contributes 0
        float mc = mask[b*LL + cc];
        if (mh != 0.f && mc != 0.f) {
            float eng = s[j] + sdv + SE[(b*KK + k)*LL + cc] + bk;
            atomicAdd(&Arow[cc], expf(eng));
            if (cc >= 1 && tags[b*LL + cc] == k && heads[b*LL + cc] == gh) {
                atomicAdd(&tgt[b], eng);        // te = eng * mh * mc, masks are 1 here
            }
        }
        // masked entries: A contribution 0, te contribution 0
    }
}

// ---------------------------------------------------------------------------
// Kernel 2: per batch: Dg = colsum(A)*(1+RTOL)+ATOL; Sub = Lap[1:,1:] with
// invalid region -> identity; LU (no pivoting; column-diag-dominant M-matrix);
// out[b] = sum(log(pivots)) - tgt[b]
// ---------------------------------------------------------------------------
__global__ __launch_bounds__(256) void k_logdet(
    const float* __restrict__ A, const int* __restrict__ lengths,
    const float* __restrict__ tgt, float* __restrict__ out)
{
    const int b = blockIdx.x;
    const int t = threadIdx.x;
    __shared__ float M[127*128];
    __shared__ float Dg[128];
    __shared__ float red[256];
    const float* Ab = A + (size_t)b*LL*LL;

    if (t < 128) {
        float s = 0.f;
        for (int hr = 0; hr < LL; ++hr) s += Ab[hr*LL + t];
        Dg[t] = s * (1.0f + 1e-4f) + 1e-6f;
    }
    __syncthreads();

    const int n1 = lengths[b] - 1;
    for (int f = t; f < 127*128; f += 256) {
        int i = f >> 7, j = f & 127;
        if (j < 127) {
            float v;
            if (i < n1 && j < n1)
                v = ((i == j) ? Dg[i+1] : 0.f) - Ab[(i+1)*LL + (j+1)];
            else
                v = (i == j) ? 1.f : 0.f;
            M[i*128 + j] = v;
        }
    }
    __syncthreads();

    for (int j = 0; j < 126; ++j) {
        float piv = M[j*128 + j];
        float inv = 1.0f / piv;
        int i = j + 1 + t;
        if (i < 127) M[i*128 + j] *= inv;
        __syncthreads();
        int nr = 126 - j;
        for (int f = t; f < nr*128; f += 256) {
            int ii = j + 1 + (f >> 7);
            int jj = f & 127;
            if (jj > j && jj < 127)
                M[ii*128 + jj] = fmaf(-M[ii*128 + j], M[j*128 + jj], M[ii*128 + jj]);
        }
        __syncthreads();
    }

    float zp = 0.f;
    if (t < 127) zp = logf(M[t*128 + t]);
    red[t] = zp;
    __syncthreads();
    for (int off = 128; off >= 1; off >>= 1) {
        if (t < off) red[t] += red[t + off];
        __syncthreads();
    }
    if (t == 0) out[b] = red[0] - tgt[b];
}

// ---------------------------------------------------------------------------
extern "C" void kernel_launch(void* const* d_in, const int* in_sizes, int n_in,
                              void* d_out, int out_size, void* d_ws, size_t ws_size,
                              hipStream_t stream) {
    const float* H    = (const float*)d_in[0];
    const float* C    = (const float*)d_in[1];
    const float* Wd   = (const float*)d_in[2];
    const float* We   = (const float*)d_in[3];
    const float* U    = (const float*)d_in[4];
    const float* bv   = (const float*)d_in[5];
    const float* mask = (const float*)d_in[6];
    const int* heads  = (const int*)d_in[7];
    const int* tags   = (const int*)d_in[8];
    const int* lens   = (const int*)d_in[9];
    float* out = (float*)d_out;

    float* ws  = (float*)d_ws;
    float* A   = ws;                          // B*L*L = 524288 floats
    float* tgt = ws + 524288;                 // 32 floats
    float* SD  = ws + 524288 + 32;            // B*K*L = 163840
    float* SE  = SD + 163840;                 // B*K*L = 163840

    // zero A and tgt (ws is poisoned before every call)
    hipMemsetAsync(ws, 0, (524288 + 32) * sizeof(float), stream);

    k_sdse<<<dim3(BB*KK), 256, 0, stream>>>(H, C, Wd, We, SD, SE);
    k_bil<<<dim3(4, KK, BB), 256, 0, stream>>>(H, C, U, bv, mask, heads, tags, SD, SE, A, tgt);
    k_logdet<<<dim3(BB), 256, 0, stream>>>(A, lens, tgt, out);
}

// Round 2
// 673.102 us; speedup vs baseline: 8.0937x; 8.0937x over previous
//
#include <hip/hip_runtime.h>
#include <hip/hip_bf16.h>

#define BB 32
#define LL 128
#define DD 400
#define KK 40
#define EE 416   // e padded to 13*32
#define SDN 50   // d-slot count (400/8)
#define SEN 52   // e-slot count (416/8)

typedef __attribute__((ext_vector_type(8)))  short  bfrag;   // 8 bf16 = 4 VGPRs
typedef __attribute__((ext_vector_type(16))) float  ffrag;   // 16 fp32 acc

static __device__ __forceinline__ short f2bf(float f) {
    union { float f; unsigned u; } v; v.f = f;
    unsigned r = (v.u + 0x7FFF + ((v.u >> 16) & 1)) >> 16;
    return (short)r;
}

// ---------------------------------------------------------------------------
// Prep: Hslots[b][sd][h][8] = bf16(H[b][h][8sd..8sd+7])
//       Cslots[b][se][c][8] = bf16(C[b][c][8se..]) with zero pad e>=400
// ---------------------------------------------------------------------------
__global__ __launch_bounds__(256) void p_hc(
    const float* __restrict__ H, const float* __restrict__ C,
    short* __restrict__ Hs, short* __restrict__ Cs)
{
    int id = blockIdx.x * 256 + threadIdx.x;
    if (id < BB*SDN*LL) {
        int b = id / (SDN*LL); int r = id % (SDN*LL);
        int sd = r / LL; int h = r % LL;
        const float* src = H + ((size_t)(b*LL + h))*DD + sd*8;
        bfrag v;
#pragma unroll
        for (int j = 0; j < 8; ++j) v[j] = f2bf(src[j]);
        *(bfrag*)(Hs + (size_t)id*8) = v;
    } else {
        id -= BB*SDN*LL;
        int b = id / (SEN*LL); int r = id % (SEN*LL);
        int se = r / LL; int c = r % LL;
        bfrag v;
#pragma unroll
        for (int j = 0; j < 8; ++j) {
            int e = se*8 + j;
            v[j] = (e < DD) ? f2bf(C[((size_t)(b*LL + c))*DD + e]) : (short)0;
        }
        *(bfrag*)(Cs + (size_t)id*8) = v;
    }
}

// Uslots[k][sd][e][8] = bf16(U[k][8sd+j][e]), zeros for e >= 400
__global__ __launch_bounds__(256) void p_u(
    const float* __restrict__ U, short* __restrict__ Us)
{
    int id = blockIdx.x * 256 + threadIdx.x;   // < 40*50*416
    int k = id / (SDN*EE); int r = id % (SDN*EE);
    int sd = r / EE; int e = r % EE;
    bfrag v;
#pragma unroll
    for (int j = 0; j < 8; ++j)
        v[j] = (e < DD) ? f2bf(U[((size_t)k*DD + sd*8 + j)*DD + e]) : (short)0;
    *(bfrag*)(Us + (size_t)id*8) = v;
}

// ---------------------------------------------------------------------------
// SD[b,k,h] = W_d[k].h[b,h]   SE[b,k,c] = W_e[k].c[b,c]   (fp32 exact)
// ---------------------------------------------------------------------------
__global__ __launch_bounds__(256) void k_sdse(
    const float* __restrict__ H, const float* __restrict__ C,
    const float* __restrict__ Wd, const float* __restrict__ We,
    float* __restrict__ SD, float* __restrict__ SE)
{
    const int k = blockIdx.x % KK;
    const int b = blockIdx.x / KK;
    const int t = threadIdx.x;
    __shared__ float wd[DD], we[DD];
    for (int f = t; f < DD; f += 256) { wd[f] = Wd[k*DD + f]; we[f] = We[k*DD + f]; }
    __syncthreads();
    const int row = t & 127;
    const float* src = (t < 128) ? (H + (size_t)(b*LL + row)*DD)
                                 : (C + (size_t)(b*LL + row)*DD);
    const float* w = (t < 128) ? wd : we;
    float s = 0.f;
    for (int d = 0; d < DD; d += 4) {
        float4 v = *(const float4*)(src + d);
        s = fmaf(v.x, w[d+0], s); s = fmaf(v.y, w[d+1], s);
        s = fmaf(v.z, w[d+2], s); s = fmaf(v.w, w[d+3], s);
    }
    if (t < 128) SD[(b*KK + k)*LL + row] = s;
    else         SE[(b*KK + k)*LL + row] = s;
}

// ---------------------------------------------------------------------------
// Main MFMA kernel. Block = (k,b), 256 thr = 4 waves, 2x2 wave grid.
// Chunk loop over e (128,128,128,32):
//   Phase1: Tt[e][h] = sum_d Ut[e][d] * h[h][d]   (A=Ut global, B=Hs global)
//   Phase2: S[h][c] += sum_e T[h][e] * c[c][e]    (A=Tbuf LDS, B=Cs global)
// Epilogue: eng = S+sd+se+bk; A8[k%8] += exp(eng); gold-arc tgt accumulate.
// ---------------------------------------------------------------------------
__global__ __launch_bounds__(256, 2) void k_mfma(
    const short* __restrict__ Hs, const short* __restrict__ Cs,
    const short* __restrict__ Us,
    const float* __restrict__ SD, const float* __restrict__ SE,
    const float* __restrict__ bvec, const float* __restrict__ mask,
    const int* __restrict__ heads, const int* __restrict__ tags,
    float* __restrict__ A8, float* __restrict__ tgt)
{
    const int k = blockIdx.x;
    const int b = blockIdx.y;
    const int t = threadIdx.x;
    const int w  = t >> 6;
    const int l  = t & 63;
    const int l31 = l & 31;
    const int kh  = l >> 5;        // 0/1
    const int wm  = w >> 1;        // phase1: e-half; phase2: h-half
    const int wn  = w & 1;         // phase1: h-half; phase2: c-half

    __shared__ short Tbuf[16*LL*8];   // [s_e(16)][h(128)][8]  32 KB

    ffrag Sacc[2][2];
#pragma unroll
    for (int a = 0; a < 2; ++a)
#pragma unroll
        for (int c2 = 0; c2 < 2; ++c2)
#pragma unroll
            for (int r = 0; r < 16; ++r) Sacc[a][c2][r] = 0.f;

    const size_t usK = (size_t)k * SDN * EE;
    const size_t hsB = (size_t)b * SDN * LL;
    const size_t csB = (size_t)b * SEN * LL;

    for (int chunk = 0; chunk < 4; ++chunk) {
        const int e0  = chunk * 128;
        const int NEc = (chunk < 3) ? 128 : 32;
        const int nmt = (NEc == 128) ? 2 : ((wm == 0) ? 1 : 0);

        // ---- Phase 1 ----
        ffrag Tacc[2][2];
#pragma unroll
        for (int a = 0; a < 2; ++a)
#pragma unroll
            for (int c2 = 0; c2 < 2; ++c2)
#pragma unroll
                for (int r = 0; r < 16; ++r) Tacc[a][c2][r] = 0.f;

        if (nmt > 0) {
            for (int ds = 0; ds < 25; ++ds) {
                const int sdl = 2*ds + kh;
                bfrag afr[2], bfr[2];
#pragma unroll
                for (int mt = 0; mt < 2; ++mt) {
                    if (mt < nmt) {
                        int eg = e0 + 64*wm + 32*mt + l31;
                        afr[mt] = *(const bfrag*)(Us + (usK + (size_t)sdl*EE + eg)*8);
                    }
                }
#pragma unroll
                for (int nt = 0; nt < 2; ++nt) {
                    int h = 64*wn + 32*nt + l31;
                    bfr[nt] = *(const bfrag*)(Hs + (hsB + (size_t)sdl*LL + h)*8);
                }
#pragma unroll
                for (int mt = 0; mt < 2; ++mt) {
                    if (mt < nmt) {
#pragma unroll
                        for (int nt = 0; nt < 2; ++nt)
                            Tacc[mt][nt] = __builtin_amdgcn_mfma_f32_32x32x16_bf16(
                                afr[mt], bfr[nt], Tacc[mt][nt], 0, 0, 0);
                    }
                }
            }
            // write Tt tiles to LDS in phase-2 A-fragment layout
#pragma unroll
            for (int mt = 0; mt < 2; ++mt) {
                if (mt < nmt) {
#pragma unroll
                    for (int nt = 0; nt < 2; ++nt) {
                        int h = 64*wn + 32*nt + l31;
#pragma unroll
                        for (int r = 0; r < 16; r += 2) {
                            int e_loc = 64*wm + 32*mt + (r&3) + 8*(r>>2) + 4*kh;
                            int s_e = e_loc >> 3, e7 = e_loc & 7;
                            unsigned lo = (unsigned short)f2bf(Tacc[mt][nt][r]);
                            unsigned hi = (unsigned short)f2bf(Tacc[mt][nt][r+1]);
                            *(unsigned*)(&Tbuf[((size_t)s_e*LL + h)*8 + e7]) =
                                lo | (hi << 16);
                        }
                    }
                }
            }
        }
        __syncthreads();

        // ---- Phase 2 ----
        const int esteps = NEc >> 4;
        for (int es = 0; es < esteps; ++es) {
            const int sel = 2*es + kh;
            bfrag afr[2], bfr[2];
#pragma unroll
            for (int at = 0; at < 2; ++at) {
                int h = 64*wm + 32*at + l31;
                afr[at] = *(const bfrag*)(&Tbuf[((size_t)sel*LL + h)*8]);
            }
#pragma unroll
            for (int bt = 0; bt < 2; ++bt) {
                int c = 64*wn + 32*bt + l31;
                int seg = (e0 >> 3) + sel;
                bfr[bt] = *(const bfrag*)(Cs + (csB + (size_t)seg*LL + c)*8);
            }
#pragma unroll
            for (int at = 0; at < 2; ++at)
#pragma unroll
                for (int bt = 0; bt < 2; ++bt)
                    Sacc[at][bt] = __builtin_amdgcn_mfma_f32_32x32x16_bf16(
                        afr[at], bfr[bt], Sacc[at][bt], 0, 0, 0);
        }
        __syncthreads();   // Tbuf reused next chunk
    }

    // ---- Epilogue ----
    const float bk = bvec[k];
    const float* SDb = SD + ((size_t)b*KK + k)*LL;
    const float* SEb = SE + ((size_t)b*KK + k)*LL;
    float* Ab = A8 + ((size_t)((k & 7)*BB + b))*LL*LL;

#pragma unroll
    for (int at = 0; at < 2; ++at) {
#pragma unroll
        for (int bt = 0; bt < 2; ++bt) {
            const int c = 64*wn + 32*bt + l31;
            const float mc = mask[b*LL + c];
            const float sev = SEb[c];
            const int headc = heads[b*LL + c];
            const int tagc  = tags[b*LL + c];
#pragma unroll
            for (int r = 0; r < 16; ++r) {
                int h = 64*wm + 32*at + (r&3) + 8*(r>>2) + 4*kh;
                if (h == c) continue;
                float mh = mask[b*LL + h];
                if (mh == 0.f || mc == 0.f) continue;
                float eng = Sacc[at][bt][r] + SDb[h] + sev + bk;
                atomicAdd(&Ab[h*LL + c], __expf(eng));
                if (c >= 1 && tagc == k && headc == h) atomicAdd(&tgt[b], eng);
            }
        }
    }
}

// ---------------------------------------------------------------------------
// Per batch: As = sum_g A8[g]; Dg = colsum; Sub -> LU (no pivot, M-matrix);
// out[b] = sum(log(piv)) - tgt[b]
// ---------------------------------------------------------------------------
__global__ __launch_bounds__(256) void k_logdet(
    const float* __restrict__ A8, const int* __restrict__ lengths,
    const float* __restrict__ tgt, float* __restrict__ out)
{
    const int b = blockIdx.x;
    const int t = threadIdx.x;
    __shared__ float As[LL*LL];      // 64 KB
    __shared__ float M[127*128];     // 65 KB
    __shared__ float Dg[128];
    __shared__ float red[256];

    for (int f = t; f < LL*LL; f += 256) {
        float s = 0.f;
#pragma unroll
        for (int g = 0; g < 8; ++g)
            s += A8[((size_t)(g*BB + b))*LL*LL + f];
        As[f] = s;
    }
    __syncthreads();

    if (t < 128) {
        float s = 0.f;
        for (int hr = 0; hr < LL; ++hr) s += As[hr*LL + t];
        Dg[t] = s * (1.0f + 1e-4f) + 1e-6f;
    }
    __syncthreads();

    const int n1 = lengths[b] - 1;
    for (int f = t; f < 127*128; f += 256) {
        int i = f >> 7, j = f & 127;
        if (j < 127) {
            float v;
            if (i < n1 && j < n1)
                v = ((i == j) ? Dg[i+1] : 0.f) - As[(i+1)*LL + (j+1)];
            else
                v = (i == j) ? 1.f : 0.f;
            M[i*128 + j] = v;
        }
    }
    __syncthreads();

    for (int j = 0; j < 126; ++j) {
        float inv = 1.0f / M[j*128 + j];
        int i = j + 1 + t;
        if (i < 127) M[i*128 + j] *= inv;
        __syncthreads();
        int nr = 126 - j;
        for (int f = t; f < nr*128; f += 256) {
            int ii = j + 1 + (f >> 7);
            int jj = f & 127;
            if (jj > j && jj < 127)
                M[ii*128 + jj] = fmaf(-M[ii*128 + j], M[j*128 + jj], M[ii*128 + jj]);
        }
        __syncthreads();
    }

    float zp = 0.f;
    if (t < 127) zp = logf(M[t*128 + t]);
    red[t] = zp;
    __syncthreads();
    for (int off = 128; off >= 1; off >>= 1) {
        if (t < off) red[t] += red[t + off];
        __syncthreads();
    }
    if (t == 0) out[b] = red[0] - tgt[b];
}

// ---------------------------------------------------------------------------
extern "C" void kernel_launch(void* const* d_in, const int* in_sizes, int n_in,
                              void* d_out, int out_size, void* d_ws, size_t ws_size,
                              hipStream_t stream) {
    const float* H    = (const float*)d_in[0];
    const float* C    = (const float*)d_in[1];
    const float* Wd   = (const float*)d_in[2];
    const float* We   = (const float*)d_in[3];
    const float* U    = (const float*)d_in[4];
    const float* bv   = (const float*)d_in[5];
    const float* mask = (const float*)d_in[6];
    const int* heads  = (const int*)d_in[7];
    const int* tags   = (const int*)d_in[8];
    const int* lens   = (const int*)d_in[9];
    float* out = (float*)d_out;

    // workspace layout
    char* p = (char*)d_ws;
    float* A8  = (float*)p;                 p += (size_t)8*BB*LL*LL*4;      // 16.78 MB
    float* tgt = (float*)p;                 p += 32*4;
    float* SDp = (float*)p;                 p += (size_t)BB*KK*LL*4;
    float* SEp = (float*)p;                 p += (size_t)BB*KK*LL*4;
    short* Hsp = (short*)p;                 p += (size_t)BB*SDN*LL*8*2;
    short* Csp = (short*)p;                 p += (size_t)BB*SEN*LL*8*2;
    short* Usp = (short*)p;                 p += (size_t)KK*SDN*EE*8*2;

    hipMemsetAsync(d_ws, 0, ((size_t)8*BB*LL*LL + 32)*4, stream);

    p_hc  <<<dim3(1632), 256, 0, stream>>>(H, C, Hsp, Csp);
    p_u   <<<dim3(3250), 256, 0, stream>>>(U, Usp);
    k_sdse<<<dim3(BB*KK), 256, 0, stream>>>(H, C, Wd, We, SDp, SEp);
    k_mfma<<<dim3(KK, BB), 256, 0, stream>>>(Hsp, Csp, Usp, SDp, SEp, bv, mask,
                                             heads, tags, A8, tgt);
    k_logdet<<<dim3(BB), 256, 0, stream>>>(A8, lens, tgt, out);
}

// Round 3
// 413.725 us; speedup vs baseline: 13.1679x; 1.6269x over previous
//
#include <hip/hip_runtime.h>
#include <hip/hip_bf16.h>

#define BB 32
#define LL 128
#define DD 400
#define KK 40
#define EE 416   // e padded to 13*32
#define SDN 50   // d-slot count (400/8)
#define SEN 52   // e-slot count (416/8)

typedef __attribute__((ext_vector_type(8)))  short  bfrag;   // 8 bf16 = 4 VGPRs
typedef __attribute__((ext_vector_type(16))) float  ffrag;   // 16 fp32 acc

static __device__ __forceinline__ short f2bf(float f) {
    union { float f; unsigned u; } v; v.f = f;
    unsigned r = (v.u + 0x7FFF + ((v.u >> 16) & 1)) >> 16;
    return (short)r;
}

// ---------------------------------------------------------------------------
// Prep: Hslots[b][sd][h][8] = bf16(H[b][h][8sd..8sd+7])
//       Cslots[b][se][c][8] = bf16(C[b][c][8se..]) with zero pad e>=400
// ---------------------------------------------------------------------------
__global__ __launch_bounds__(256) void p_hc(
    const float* __restrict__ H, const float* __restrict__ C,
    short* __restrict__ Hs, short* __restrict__ Cs)
{
    int id = blockIdx.x * 256 + threadIdx.x;
    if (id < BB*SDN*LL) {
        int b = id / (SDN*LL); int r = id % (SDN*LL);
        int sd = r / LL; int h = r % LL;
        const float* src = H + ((size_t)(b*LL + h))*DD + sd*8;
        bfrag v;
#pragma unroll
        for (int j = 0; j < 8; ++j) v[j] = f2bf(src[j]);
        *(bfrag*)(Hs + (size_t)id*8) = v;
    } else {
        id -= BB*SDN*LL;
        int b = id / (SEN*LL); int r = id % (SEN*LL);
        int se = r / LL; int c = r % LL;
        bfrag v;
#pragma unroll
        for (int j = 0; j < 8; ++j) {
            int e = se*8 + j;
            v[j] = (e < DD) ? f2bf(C[((size_t)(b*LL + c))*DD + e]) : (short)0;
        }
        *(bfrag*)(Cs + (size_t)id*8) = v;
    }
}

// Uslots[k][sd][e][8] = bf16(U[k][8sd+j][e]), zeros for e >= 400
__global__ __launch_bounds__(256) void p_u(
    const float* __restrict__ U, short* __restrict__ Us)
{
    int id = blockIdx.x * 256 + threadIdx.x;   // < 40*50*416
    int k = id / (SDN*EE); int r = id % (SDN*EE);
    int sd = r / EE; int e = r % EE;
    bfrag v;
#pragma unroll
    for (int j = 0; j < 8; ++j)
        v[j] = (e < DD) ? f2bf(U[((size_t)k*DD + sd*8 + j)*DD + e]) : (short)0;
    *(bfrag*)(Us + (size_t)id*8) = v;
}

// ---------------------------------------------------------------------------
// SD[b,k,h] = W_d[k].h[b,h]   SE[b,k,c] = W_e[k].c[b,c]   (fp32 exact)
// ---------------------------------------------------------------------------
__global__ __launch_bounds__(256) void k_sdse(
    const float* __restrict__ H, const float* __restrict__ C,
    const float* __restrict__ Wd, const float* __restrict__ We,
    float* __restrict__ SD, float* __restrict__ SE)
{
    const int k = blockIdx.x % KK;
    const int b = blockIdx.x / KK;
    const int t = threadIdx.x;
    __shared__ float wd[DD], we[DD];
    for (int f = t; f < DD; f += 256) { wd[f] = Wd[k*DD + f]; we[f] = We[k*DD + f]; }
    __syncthreads();
    const int row = t & 127;
    const float* src = (t < 128) ? (H + (size_t)(b*LL + row)*DD)
                                 : (C + (size_t)(b*LL + row)*DD);
    const float* w = (t < 128) ? wd : we;
    float s = 0.f;
    for (int d = 0; d < DD; d += 4) {
        float4 v = *(const float4*)(src + d);
        s = fmaf(v.x, w[d+0], s); s = fmaf(v.y, w[d+1], s);
        s = fmaf(v.z, w[d+2], s); s = fmaf(v.w, w[d+3], s);
    }
    if (t < 128) SD[(b*KK + k)*LL + row] = s;
    else         SE[(b*KK + k)*LL + row] = s;
}

// ---------------------------------------------------------------------------
// Main MFMA kernel (unchanged from round 2).
// ---------------------------------------------------------------------------
__global__ __launch_bounds__(256, 2) void k_mfma(
    const short* __restrict__ Hs, const short* __restrict__ Cs,
    const short* __restrict__ Us,
    const float* __restrict__ SD, const float* __restrict__ SE,
    const float* __restrict__ bvec, const float* __restrict__ mask,
    const int* __restrict__ heads, const int* __restrict__ tags,
    float* __restrict__ A8, float* __restrict__ tgt)
{
    const int k = blockIdx.x;
    const int b = blockIdx.y;
    const int t = threadIdx.x;
    const int w  = t >> 6;
    const int l  = t & 63;
    const int l31 = l & 31;
    const int kh  = l >> 5;        // 0/1
    const int wm  = w >> 1;        // phase1: e-half; phase2: h-half
    const int wn  = w & 1;         // phase1: h-half; phase2: c-half

    __shared__ short Tbuf[16*LL*8];   // [s_e(16)][h(128)][8]  32 KB

    ffrag Sacc[2][2];
#pragma unroll
    for (int a = 0; a < 2; ++a)
#pragma unroll
        for (int c2 = 0; c2 < 2; ++c2)
#pragma unroll
            for (int r = 0; r < 16; ++r) Sacc[a][c2][r] = 0.f;

    const size_t usK = (size_t)k * SDN * EE;
    const size_t hsB = (size_t)b * SDN * LL;
    const size_t csB = (size_t)b * SEN * LL;

    for (int chunk = 0; chunk < 4; ++chunk) {
        const int e0  = chunk * 128;
        const int NEc = (chunk < 3) ? 128 : 32;
        const int nmt = (NEc == 128) ? 2 : ((wm == 0) ? 1 : 0);

        // ---- Phase 1 ----
        ffrag Tacc[2][2];
#pragma unroll
        for (int a = 0; a < 2; ++a)
#pragma unroll
            for (int c2 = 0; c2 < 2; ++c2)
#pragma unroll
                for (int r = 0; r < 16; ++r) Tacc[a][c2][r] = 0.f;

        if (nmt > 0) {
            for (int ds = 0; ds < 25; ++ds) {
                const int sdl = 2*ds + kh;
                bfrag afr[2], bfr[2];
#pragma unroll
                for (int mt = 0; mt < 2; ++mt) {
                    if (mt < nmt) {
                        int eg = e0 + 64*wm + 32*mt + l31;
                        afr[mt] = *(const bfrag*)(Us + (usK + (size_t)sdl*EE + eg)*8);
                    }
                }
#pragma unroll
                for (int nt = 0; nt < 2; ++nt) {
                    int h = 64*wn + 32*nt + l31;
                    bfr[nt] = *(const bfrag*)(Hs + (hsB + (size_t)sdl*LL + h)*8);
                }
#pragma unroll
                for (int mt = 0; mt < 2; ++mt) {
                    if (mt < nmt) {
#pragma unroll
                        for (int nt = 0; nt < 2; ++nt)
                            Tacc[mt][nt] = __builtin_amdgcn_mfma_f32_32x32x16_bf16(
                                afr[mt], bfr[nt], Tacc[mt][nt], 0, 0, 0);
                    }
                }
            }
            // write Tt tiles to LDS in phase-2 A-fragment layout
#pragma unroll
            for (int mt = 0; mt < 2; ++mt) {
                if (mt < nmt) {
#pragma unroll
                    for (int nt = 0; nt < 2; ++nt) {
                        int h = 64*wn + 32*nt + l31;
#pragma unroll
                        for (int r = 0; r < 16; r += 2) {
                            int e_loc = 64*wm + 32*mt + (r&3) + 8*(r>>2) + 4*kh;
                            int s_e = e_loc >> 3, e7 = e_loc & 7;
                            unsigned lo = (unsigned short)f2bf(Tacc[mt][nt][r]);
                            unsigned hi = (unsigned short)f2bf(Tacc[mt][nt][r+1]);
                            *(unsigned*)(&Tbuf[((size_t)s_e*LL + h)*8 + e7]) =
                                lo | (hi << 16);
                        }
                    }
                }
            }
        }
        __syncthreads();

        // ---- Phase 2 ----
        const int esteps = NEc >> 4;
        for (int es = 0; es < esteps; ++es) {
            const int sel = 2*es + kh;
            bfrag afr[2], bfr[2];
#pragma unroll
            for (int at = 0; at < 2; ++at) {
                int h = 64*wm + 32*at + l31;
                afr[at] = *(const bfrag*)(&Tbuf[((size_t)sel*LL + h)*8]);
            }
#pragma unroll
            for (int bt = 0; bt < 2; ++bt) {
                int c = 64*wn + 32*bt + l31;
                int seg = (e0 >> 3) + sel;
                bfr[bt] = *(const bfrag*)(Cs + (csB + (size_t)seg*LL + c)*8);
            }
#pragma unroll
            for (int at = 0; at < 2; ++at)
#pragma unroll
                for (int bt = 0; bt < 2; ++bt)
                    Sacc[at][bt] = __builtin_amdgcn_mfma_f32_32x32x16_bf16(
                        afr[at], bfr[bt], Sacc[at][bt], 0, 0, 0);
        }
        __syncthreads();   // Tbuf reused next chunk
    }

    // ---- Epilogue ----
    const float bk = bvec[k];
    const float* SDb = SD + ((size_t)b*KK + k)*LL;
    const float* SEb = SE + ((size_t)b*KK + k)*LL;
    float* Ab = A8 + ((size_t)((k & 7)*BB + b))*LL*LL;

#pragma unroll
    for (int at = 0; at < 2; ++at) {
#pragma unroll
        for (int bt = 0; bt < 2; ++bt) {
            const int c = 64*wn + 32*bt + l31;
            const float mc = mask[b*LL + c];
            const float sev = SEb[c];
            const int headc = heads[b*LL + c];
            const int tagc  = tags[b*LL + c];
#pragma unroll
            for (int r = 0; r < 16; ++r) {
                int h = 64*wm + 32*at + (r&3) + 8*(r>>2) + 4*kh;
                if (h == c) continue;
                float mh = mask[b*LL + h];
                if (mh == 0.f || mc == 0.f) continue;
                float eng = Sacc[at][bt][r] + SDb[h] + sev + bk;
                atomicAdd(&Ab[h*LL + c], __expf(eng));
                if (c >= 1 && tagc == k && headc == h) atomicAdd(&tgt[b], eng);
            }
        }
    }
}

// ---------------------------------------------------------------------------
// Register-resident LU logdet. One block/batch, 256 thr = 16x16 grid,
// thread (rg,cg) owns the 8x8 sub-block rows 8rg..8rg+7, cols 8cg..8cg+7
// of the 128x128 padded Sub matrix (row/col 127 = identity).
// Per pivot step: owners publish col j / row j from regs to LDS, barrier,
// all threads rank-1-update their 8x8 block in registers, barrier.
// Dead rows/cols update unpredicated (they zero out; identity-row
// multipliers are 0 so the n1-masked region stays exact).
// ---------------------------------------------------------------------------
__global__ __launch_bounds__(256) void k_logdet(
    const float* __restrict__ A8, const int* __restrict__ lengths,
    const float* __restrict__ tgt, float* __restrict__ out)
{
    const int b = blockIdx.x;
    const int t = threadIdx.x;
    const int rg = t >> 4;      // 0..15 row-group
    const int cg = t & 15;      // 0..15 col-group

    __shared__ float As[LL*LL];     // 64 KB
    __shared__ float Dg[128];       // col sums, then pivot stash
    __shared__ float Lbuf[128];
    __shared__ float Ubuf[128];
    __shared__ float red[256];

    // As = sum over 8 slices (vectorized)
    const float4* A4 = (const float4*)A8;
    for (int f4 = t; f4 < 4096; f4 += 256) {
        float4 s = make_float4(0.f, 0.f, 0.f, 0.f);
#pragma unroll
        for (int g = 0; g < 8; ++g) {
            float4 v = A4[((size_t)(g*BB + b))*4096 + f4];
            s.x += v.x; s.y += v.y; s.z += v.z; s.w += v.w;
        }
        ((float4*)As)[f4] = s;
    }
    __syncthreads();

    if (t < 128) {
        float s = 0.f;
        for (int hr = 0; hr < LL; ++hr) s += As[hr*LL + t];
        Dg[t] = s * (1.0f + 1e-4f) + 1e-6f;
    }
    __syncthreads();

    // Build register block: Sub coords i = 8rg+r, j = 8cg+c (0..127; 127 = pad)
    const int n1 = lengths[b] - 1;
    float m[8][8];
#pragma unroll
    for (int r = 0; r < 8; ++r) {
        const int i = 8*rg + r;
#pragma unroll
        for (int c = 0; c < 8; ++c) {
            const int j = 8*cg + c;
            float v;
            if (i < n1 && j < n1)
                v = ((i == j) ? Dg[i+1] : 0.f) - As[(i+1)*LL + (j+1)];
            else
                v = (i == j) ? 1.f : 0.f;
            m[r][c] = v;
        }
    }
    __syncthreads();   // done reading Dg/As; Dg reused as pivot stash

    // LU, 127 pivots
    for (int j = 0; j < 127; ++j) {
        const int jg = j >> 3, jl = j & 7;
        if (cg == jg) {
#pragma unroll
            for (int c = 0; c < 8; ++c) {
                if (c == jl) {   // wave-uniform scalar branch
#pragma unroll
                    for (int r = 0; r < 8; ++r) Lbuf[8*rg + r] = m[r][c];
                }
            }
        }
        if (rg == jg) {
#pragma unroll
            for (int r = 0; r < 8; ++r) {
                if (r == jl) {
#pragma unroll
                    for (int c = 0; c < 8; ++c) Ubuf[8*cg + c] = m[r][c];
                }
            }
        }
        __syncthreads();

        const float piv = Lbuf[j];
        if (t == j) Dg[j] = piv;          // stash pivot for the log pass
        const float rp = 1.0f / piv;
        float lr[8], ur[8];
#pragma unroll
        for (int r = 0; r < 8; ++r) lr[r] = Lbuf[8*rg + r] * rp;
#pragma unroll
        for (int c = 0; c < 8; ++c) ur[c] = Ubuf[8*cg + c];
#pragma unroll
        for (int r = 0; r < 8; ++r)
#pragma unroll
            for (int c = 0; c < 8; ++c)
                m[r][c] = fmaf(-lr[r], ur[c], m[r][c]);
        __syncthreads();
    }

    float lsum = 0.f;
    if (t < 127) lsum = logf(Dg[t]);
    red[t] = lsum;
    __syncthreads();
    for (int off = 128; off >= 1; off >>= 1) {
        if (t < off) red[t] += red[t + off];
        __syncthreads();
    }
    if (t == 0) out[b] = red[0] - tgt[b];
}

// ---------------------------------------------------------------------------
extern "C" void kernel_launch(void* const* d_in, const int* in_sizes, int n_in,
                              void* d_out, int out_size, void* d_ws, size_t ws_size,
                              hipStream_t stream) {
    const float* H    = (const float*)d_in[0];
    const float* C    = (const float*)d_in[1];
    const float* Wd   = (const float*)d_in[2];
    const float* We   = (const float*)d_in[3];
    const float* U    = (const float*)d_in[4];
    const float* bv   = (const float*)d_in[5];
    const float* mask = (const float*)d_in[6];
    const int* heads  = (const int*)d_in[7];
    const int* tags   = (const int*)d_in[8];
    const int* lens   = (const int*)d_in[9];
    float* out = (float*)d_out;

    // workspace layout
    char* p = (char*)d_ws;
    float* A8  = (float*)p;                 p += (size_t)8*BB*LL*LL*4;      // 16.78 MB
    float* tgt = (float*)p;                 p += 32*4;
    float* SDp = (float*)p;                 p += (size_t)BB*KK*LL*4;
    float* SEp = (float*)p;                 p += (size_t)BB*KK*LL*4;
    short* Hsp = (short*)p;                 p += (size_t)BB*SDN*LL*8*2;
    short* Csp = (short*)p;                 p += (size_t)BB*SEN*LL*8*2;
    short* Usp = (short*)p;                 p += (size_t)KK*SDN*EE*8*2;

    hipMemsetAsync(d_ws, 0, ((size_t)8*BB*LL*LL + 32)*4, stream);

    p_hc  <<<dim3(1632), 256, 0, stream>>>(H, C, Hsp, Csp);
    p_u   <<<dim3(3250), 256, 0, stream>>>(U, Usp);
    k_sdse<<<dim3(BB*KK), 256, 0, stream>>>(H, C, Wd, We, SDp, SEp);
    k_mfma<<<dim3(KK, BB), 256, 0, stream>>>(Hsp, Csp, Usp, SDp, SEp, bv, mask,
                                             heads, tags, A8, tgt);
    k_logdet<<<dim3(BB), 256, 0, stream>>>(A8, lens, tgt, out);
}